// Round 10
// baseline (350.360 us; speedup 1.0000x reference)
//
#include <hip/hip_runtime.h>
#include <hip/hip_bf16.h>

typedef __attribute__((ext_vector_type(8))) short short8;
typedef __attribute__((ext_vector_type(4))) float f32x4;
typedef __attribute__((ext_vector_type(4))) float float4v;
typedef __attribute__((ext_vector_type(4))) unsigned short ushort4v;

// RNE float -> bf16 payload
__device__ __forceinline__ unsigned short f2bf(float f) {
    union { float f; unsigned u; } x; x.f = f;
    unsigned r = x.u + 0x7FFFu + ((x.u >> 16) & 1u);
    return (unsigned short)(r >> 16);
}

// C[k][n] = s(k) * cos(pi * k * (2n+1) / (2N)), N = 512, ortho norm.
__global__ __launch_bounds__(256) void make_dct_mat(unsigned short* __restrict__ Cm) {
    int idx = blockIdx.x * 256 + threadIdx.x;     // 0 .. 512*512-1
    int k = idx >> 9;
    int n = idx & 511;
    int m = (k * (2 * n + 1)) & 2047;             // mod 4N (N=512)
    float ang = (3.14159265358979323846f / 1024.0f) * (float)m;
    float s = (k == 0) ? 0.04419417382415922f : 0.0625f;  // 1/sqrt(512), sqrt(2/512)
    Cm[idx] = f2bf(s * cosf(ang));
}

#define GLD16(g, l) __builtin_amdgcn_global_load_lds( \
    (const __attribute__((address_space(1))) void*)(g), \
    (__attribute__((address_space(3))) void*)(l), 16, 0, 0)

// D[img] = A * B[img]^T  (512x512 row-major per image).
// Block: BM=512 (all output rows) x BN=64 col strip.
// NEW STRUCTURE (barrier-free K-loop):
//   - B panel (64 rows x 512 K, bf16) staged into LDS ONCE (64 KB, one barrier).
//     LDS layout: 16 K-subtiles of [64 rows][4 x 16B slots], proven XOR swizzle
//     slotL = slotG ^ ((row>>1)&3) -> zero bank conflicts on ds_read_b128.
//   - A (= DCT matrix C, 512 KB, shared by ALL blocks -> permanently L2-hot)
//     is read per K-step directly from global into registers. Waves partition
//     rows, so each block reads each A element exactly once.
//   - K-loop: 16 unrolled iters of {4 L2 loads, 4 ds_read_b128, 16 MFMA},
//     NO barriers -> waves run free; compiler pipelines; 2 blocks/CU TLP.
template <bool B_IS_F32, bool OUT_F32>
__device__ __forceinline__ void dct_gemm_body(
    const unsigned short* __restrict__ A,
    const void* __restrict__ Ball,
    void* __restrict__ Dall)
{
    __shared__ unsigned short Bs[16][64 * 32];   // 64 KB total

    // XCD-bijective swizzle (2048 % 8 == 0); an image's 8 strips stay on one XCD.
    int wg  = blockIdx.x;
    int cpx = gridDim.x >> 3;
    int swz = (wg & 7) * cpx + (wg >> 3);
    int img = swz >> 3;
    int C0  = (swz & 7) * 64;     // output-column strip

    int t    = threadIdx.x;       // 0..511
    int lane = t & 63;
    int wid  = t >> 6;            // 0..7 -> output rows [wid*64, +64)

    const size_t imgoff = (size_t)img * (512 * 512);

    // ---- stage the whole B panel once ----
    if constexpr (B_IS_F32) {
        // fp32 -> bf16 in regs -> ds_write. 8B output granule g = kt*512 + row*8 + sL*2 + half.
        const float* Bp = (const float*)Ball + imgoff;
        #pragma unroll
        for (int p = 0; p < 16; ++p) {
            int g    = p * 512 + t;          // 0..8191
            int kt   = g >> 9;
            int gg   = g & 511;
            int row  = gg >> 3;
            int sL   = (gg >> 1) & 3;
            int half = gg & 1;
            int sG   = sL ^ ((row >> 1) & 3);
            float4v v = *(const float4v*)(Bp + (size_t)(C0 + row) * 512
                                          + kt * 32 + sG * 8 + half * 4);
            ushort4v pk;
            pk.x = f2bf(v.x); pk.y = f2bf(v.y); pk.z = f2bf(v.z); pk.w = f2bf(v.w);
            *(ushort4v*)((unsigned short*)Bs + (size_t)g * 4) = pk;
        }
    } else {
        // bf16 via global_load_lds w=16. 16B slot s = kt*256 + row*4 + slotL.
        const unsigned short* Bp = (const unsigned short*)Ball + imgoff;
        #pragma unroll
        for (int p = 0; p < 8; ++p) {
            int s    = p * 512 + t;          // 0..4095
            int kt   = s >> 8;
            int tt   = s & 255;
            int row  = tt >> 2;
            int sG   = (tt & 3) ^ ((row >> 1) & 3);
            GLD16(Bp + (size_t)(C0 + row) * 512 + kt * 32 + sG * 8,
                  (unsigned short*)Bs + (size_t)s * 8);
        }
    }
    __syncthreads();   // the ONLY barrier

    // ---- barrier-free K loop ----
    // A fragment for wave wid: rows wid*64 + m*16 + (lane&15), K-slot (lane>>4)*8.
    const unsigned short* gA = A + (size_t)(wid * 64 + (lane & 15)) * 512 + (lane >> 4) * 8;
    const int roff = ((lane >> 4) ^ ((lane >> 1) & 3)) * 8;   // proven read swizzle

    f32x4 acc[4][4] = {};   // 64 VGPR
    #pragma unroll
    for (int kt = 0; kt < 16; ++kt) {
        short8 av[4], bv[4];
        #pragma unroll
        for (int m = 0; m < 4; ++m)
            av[m] = *(const short8*)(gA + (size_t)m * 16 * 512 + kt * 32);
        #pragma unroll
        for (int n = 0; n < 4; ++n)
            bv[n] = *(const short8*)(&Bs[kt][(n * 16 + (lane & 15)) * 32 + roff]);
        __builtin_amdgcn_s_setprio(1);
        #pragma unroll
        for (int m = 0; m < 4; ++m)
            #pragma unroll
            for (int n = 0; n < 4; ++n)
                acc[m][n] = __builtin_amdgcn_mfma_f32_16x16x32_bf16(
                                av[m], bv[n], acc[m][n], 0, 0, 0);
        __builtin_amdgcn_s_setprio(0);
    }

    // ---- epilogue: C/D layout col = lane&15, row = (lane>>4)*4 + reg ----
    int r0 = wid * 64 + (lane >> 4) * 4;
    int c0 = C0 + (lane & 15);
    if constexpr (OUT_F32) {
        float* D = (float*)Dall + imgoff;
        #pragma unroll
        for (int m = 0; m < 4; ++m)
            #pragma unroll
            for (int n = 0; n < 4; ++n)
                #pragma unroll
                for (int r = 0; r < 4; ++r)
                    D[(size_t)(r0 + m * 16 + r) * 512 + c0 + n * 16] = acc[m][n][r];
    } else {
        unsigned short* D = (unsigned short*)Dall + imgoff;
        #pragma unroll
        for (int m = 0; m < 4; ++m)
            #pragma unroll
            for (int n = 0; n < 4; ++n)
                #pragma unroll
                for (int r = 0; r < 4; ++r)
                    D[(size_t)(r0 + m * 16 + r) * 512 + c0 + n * 16] = f2bf(acc[m][n][r]);
    }
}

__global__ __launch_bounds__(512, 4) void dct_gemm_s1(
    const unsigned short* __restrict__ A, const float* __restrict__ B,
    unsigned short* __restrict__ D) {
    dct_gemm_body<true, false>(A, B, D);
}

__global__ __launch_bounds__(512, 4) void dct_gemm_s2(
    const unsigned short* __restrict__ A, const unsigned short* __restrict__ B,
    float* __restrict__ D) {
    dct_gemm_body<false, true>(A, B, D);
}

extern "C" void kernel_launch(void* const* d_in, const int* in_sizes, int n_in,
                              void* d_out, int out_size, void* d_ws, size_t ws_size,
                              hipStream_t stream) {
    const float* x = (const float*)d_in[0];
    float* out = (float*)d_out;

    // ws layout: [0, 512KB) = C matrix bf16; [1MB, 1MB+128MB) = intermediate T' bf16
    unsigned short* Cm = (unsigned short*)d_ws;
    unsigned short* Tm = (unsigned short*)((char*)d_ws + (1 << 20));

    int nimg = in_sizes[0] / (512 * 512);   // 256

    make_dct_mat<<<dim3(1024), dim3(256), 0, stream>>>(Cm);
    // Stage 1: T'[b] = C * X[b]^T   (B = fp32 -> cvt in regs -> bf16 LDS, out = bf16)
    dct_gemm_s1<<<dim3(nimg * 8), dim3(512), 0, stream>>>(Cm, x, Tm);
    // Stage 2: Y[b] = C * T'[b]^T = C X C^T  (B = bf16 via global_load_lds, out = fp32)
    dct_gemm_s2<<<dim3(nimg * 8), dim3(512), 0, stream>>>(Cm, Tm, out);
}